// Round 1
// baseline (566.072 us; speedup 1.0000x reference)
//
#include <hip/hip_runtime.h>

#define N_ 4096
#define M_ 10
#define T_ 10
#define B_ 1024
#define P_ 1024
#define AD_ 64

__device__ __forceinline__ float wave_red_sum(float v) {
#pragma unroll
  for (int m = 32; m >= 1; m >>= 1) v += __shfl_xor(v, m);
  return v;
}

// Copy initial state post0/pre0 -> workspace (must redo every launch: state evolves).
__global__ void k_init(const float* __restrict__ post0, const float* __restrict__ pre0,
                       float* __restrict__ post, float* __restrict__ pre) {
  int i = blockIdx.x * blockDim.x + threadIdx.x;
  if (i < N_ * M_) { post[i] = post0[i]; pre[i] = pre0[i]; }
}

// Fused encoder: fx -> E1(LN,relu) -> E2(LN,relu) -> enc -> values. 4 batch rows/block.
__global__ __launch_bounds__(128)
void k_enc(const float* __restrict__ x,
           const float* __restrict__ w1, const float* __restrict__ b1,
           const float* __restrict__ g1, const float* __restrict__ be1,
           const float* __restrict__ w2, const float* __restrict__ b2,
           const float* __restrict__ g2, const float* __restrict__ be2,
           const float* __restrict__ w3, const float* __restrict__ b3,
           const float* __restrict__ vw, const float* __restrict__ vb,
           float* __restrict__ enc_g, float* __restrict__ values_g) {
  const int tid = threadIdx.x;
  const int b0 = blockIdx.x * 4;
  __shared__ float fx[4][784];
  __shared__ float e1[4][128];
  __shared__ float e2[4][32];
  __shared__ float encs[4][4];
  __shared__ float red[2][4][2];

  for (int i = tid; i < 4 * 784; i += 128) {
    int r = i / 784, k = i - r * 784;
    fx[r][k] = x[(b0 + r) * 784 + k];
  }
  __syncthreads();

  float acc[4] = {0.f, 0.f, 0.f, 0.f};
  for (int k = 0; k < 784; ++k) {
    float w = w1[k * 128 + tid];
#pragma unroll
    for (int r = 0; r < 4; ++r) acc[r] += fx[r][k] * w;
  }
  float bb1 = b1[tid];
#pragma unroll
  for (int r = 0; r < 4; ++r) acc[r] += bb1;

  int wid = tid >> 6, lane = tid & 63;
  float s[4], s2[4];
#pragma unroll
  for (int r = 0; r < 4; ++r) { s[r] = wave_red_sum(acc[r]); s2[r] = wave_red_sum(acc[r] * acc[r]); }
  if (lane == 0) {
#pragma unroll
    for (int r = 0; r < 4; ++r) { red[wid][r][0] = s[r]; red[wid][r][1] = s2[r]; }
  }
  __syncthreads();
  float gg = g1[tid], bbe = be1[tid];
#pragma unroll
  for (int r = 0; r < 4; ++r) {
    float S = red[0][r][0] + red[1][r][0];
    float S2 = red[0][r][1] + red[1][r][1];
    float m = S * (1.f / 128.f);
    float v = S2 * (1.f / 128.f) - m * m;
    float y = (acc[r] - m) * rsqrtf(v + 1e-5f) * gg + bbe;
    e1[r][tid] = fmaxf(y, 0.f);
  }
  __syncthreads();

  {  // E2: thread t -> row r=t>>5, out j=t&31; LN over 32 via width-32 shuffles
    int r = tid >> 5, j = tid & 31;
    float u = b2[j];
    for (int k = 0; k < 128; ++k) u += e1[r][k] * w2[k * 32 + j];
    float ss = u, ss2 = u * u;
#pragma unroll
    for (int m = 16; m >= 1; m >>= 1) { ss += __shfl_xor(ss, m, 32); ss2 += __shfl_xor(ss2, m, 32); }
    float mm = ss * (1.f / 32.f), vv = ss2 * (1.f / 32.f) - mm * mm;
    float y = (u - mm) * rsqrtf(vv + 1e-5f) * g2[j] + be2[j];
    e2[r][j] = fmaxf(y, 0.f);
  }
  __syncthreads();

  if (tid < 16) {  // enc: 4 rows x 4 outs
    int r = tid >> 2, o = tid & 3;
    float u = b3[o];
    for (int k = 0; k < 32; ++k) u += e2[r][k] * w3[k * 4 + o];
    encs[r][o] = u;
    enc_g[(b0 + r) * 4 + o] = u;
  }
  __syncthreads();

  {  // values: 4 rows x 64 (attention softmax over size-1 axis == 1, so att == values)
    int v = tid & 63;
    int rbase = tid >> 6;
#pragma unroll
    for (int rr = 0; rr < 2; ++rr) {
      int r = rbase + rr * 2;
      float u = vb[v];
#pragma unroll
      for (int o = 0; o < 4; ++o) u += encs[r][o] * vw[o * 64 + v];
      values_g[(b0 + r) * 64 + v] = u;
    }
  }
}

// c_part[blk][j] = sum_{n in chunk} post_last[n] * sy_w1[4+n][j]   (16 blocks x 256)
__global__ __launch_bounds__(256)
void k_synA(const float* __restrict__ post, const float* __restrict__ syw1,
            float* __restrict__ c_part) {
  int j = threadIdx.x;
  int n0 = blockIdx.x * 256;
  float acc = 0.f;
  for (int n = n0; n < n0 + 256; ++n)
    acc += post[n * M_ + (M_ - 1)] * syw1[(4 + n) * 256 + j];
  c_part[blockIdx.x * 256 + j] = acc;
}

// h[b][j] = relu(ln_j(c_j + enc[b] @ sy_w1[:4] , sy_g, sy_be))   (1024 blocks x 256)
__global__ __launch_bounds__(256)
void k_synB(const float* __restrict__ c_part, const float* __restrict__ enc_g,
            const float* __restrict__ syw1, const float* __restrict__ syb1,
            const float* __restrict__ syg, const float* __restrict__ sybe,
            float* __restrict__ h) {
  int j = threadIdx.x;
  int b = blockIdx.x;
  float u = syb1[j];
#pragma unroll
  for (int r = 0; r < 16; ++r) u += c_part[r * 256 + j];
#pragma unroll
  for (int o = 0; o < 4; ++o) u += enc_g[b * 4 + o] * syw1[o * 256 + j];
  __shared__ float red[8];
  float s = wave_red_sum(u), s2 = wave_red_sum(u * u);
  int wid = j >> 6, lane = j & 63;
  if (lane == 0) { red[wid * 2] = s; red[wid * 2 + 1] = s2; }
  __syncthreads();
  float S = red[0] + red[2] + red[4] + red[6];
  float S2 = red[1] + red[3] + red[5] + red[7];
  float m = S * (1.f / 256.f), v = S2 * (1.f / 256.f) - m * m;
  float y = (u - m) * rsqrtf(v + 1e-5f) * syg[j] + sybe[j];
  h[b * 256 + j] = fmaxf(y, 0.f);
}

// hb_part[r][j] = sum over a 128-row slab of h   (8 blocks x 256)
__global__ __launch_bounds__(256)
void k_colred(const float* __restrict__ h, float* __restrict__ hb_part) {
  int j = threadIdx.x;
  int r = blockIdx.x;
  float acc = 0.f;
  for (int b = r * 128; b < r * 128 + 128; ++b) acc += h[b * 256 + j];
  hb_part[r * 256 + j] = acc;
}

// npre[n] = hbar @ sy_w2 + sy_b2 ; shift pre row, append.  (16 blocks x 256)
__global__ __launch_bounds__(256)
void k_pre(const float* __restrict__ hb_part, const float* __restrict__ syw2,
           const float* __restrict__ syb2, float* __restrict__ pre) {
  __shared__ float hbar[256];
  int tid = threadIdx.x;
  float acc = 0.f;
#pragma unroll
  for (int r = 0; r < 8; ++r) acc += hb_part[r * 256 + tid];
  hbar[tid] = acc * (1.f / 1024.f);
  __syncthreads();
  int n = blockIdx.x * 256 + tid;
  float u = syb2[n];
  for (int k = 0; k < 256; ++k) u += hbar[k] * syw2[k * N_ + n];
  float row[M_];
#pragma unroll
  for (int m = 1; m < M_; ++m) row[m - 1] = pre[n * M_ + m];
  row[M_ - 1] = u;
#pragma unroll
  for (int m = 0; m < M_; ++m) pre[n * M_ + m] = row[m];
}

// Neuromodulator: per n: LN128(pre[n] @ nm_w1[n] + b1) relu, dot nm_w2[n]; shift post.
// 2048 blocks x 256 (2 rows per block, 128 threads per row)
__global__ __launch_bounds__(256)
void k_nm(const float* __restrict__ pre, const float* __restrict__ w1,
          const float* __restrict__ b1, const float* __restrict__ g,
          const float* __restrict__ be, const float* __restrict__ w2,
          const float* __restrict__ b2, float* __restrict__ post) {
  int tid = threadIdx.x;
  int grp = tid >> 7;
  int j = tid & 127;
  int n = blockIdx.x * 2 + grp;
  float prow[M_];
#pragma unroll
  for (int m = 0; m < M_; ++m) prow[m] = pre[n * M_ + m];
  float u = b1[n * 128 + j];
#pragma unroll
  for (int m = 0; m < M_; ++m) u += prow[m] * w1[(n * M_ + m) * 128 + j];
  __shared__ float red[8];
  float s = wave_red_sum(u), s2 = wave_red_sum(u * u);
  int wid = tid >> 6, lane = tid & 63;
  if (lane == 0) { red[wid * 2] = s; red[wid * 2 + 1] = s2; }
  __syncthreads();
  float S = red[grp * 4 + 0] + red[grp * 4 + 2];
  float S2 = red[grp * 4 + 1] + red[grp * 4 + 3];
  float m = S * (1.f / 128.f), v = S2 * (1.f / 128.f) - m * m;
  float y = (u - m) * rsqrtf(v + 1e-5f) * g[n * 128 + j] + be[n * 128 + j];
  y = fmaxf(y, 0.f);
  float d = y * w2[n * 128 + j];
  d = wave_red_sum(d);
  __syncthreads();
  if (lane == 0) red[wid] = d;
  __syncthreads();
  if (j == 0) {
    float npost = red[grp * 2] + red[grp * 2 + 1] + b2[n];
    float row[M_];
#pragma unroll
    for (int m2 = 1; m2 < M_; ++m2) row[m2 - 1] = post[n * M_ + m2];
    row[M_ - 1] = npost;
#pragma unroll
    for (int m2 = 0; m2 < M_; ++m2) post[n * M_ + m2] = row[m2];
  }
}

// sync[p] over final post (tick 9 => L = M = 10, full rows).  (4 blocks x 256)
__global__ __launch_bounds__(256)
void k_sync(const float* __restrict__ post, const int* __restrict__ pairs,
            const float* __restrict__ decay, float* __restrict__ syncv) {
  int p = blockIdx.x * 256 + threadIdx.x;
  if (p >= P_) return;
  int i = pairs[p * 2], jn = pairs[p * 2 + 1];
  float dc = decay[p];
  float num = 0.f, den = 0.f;
#pragma unroll
  for (int l = 0; l < M_; ++l) {
    float r = expf(-dc * (float)(M_ - 1 - l));
    num += post[i * M_ + l] * r * post[jn * M_ + l];
    den += r;
  }
  syncv[p] = num / (den + 1e-8f);
}

// sc_part[pb][j] partial of (sync @ rd_w1[64:] + rd_b1)  (8 blocks x 256)
__global__ __launch_bounds__(256)
void k_scpart(const float* __restrict__ syncv, const float* __restrict__ rdw1,
              const float* __restrict__ rdb1, float* __restrict__ sc_part) {
  int j = (blockIdx.x & 1) * 256 + threadIdx.x;
  int pb = blockIdx.x >> 1;
  float acc = (pb == 0) ? rdb1[j] : 0.f;
  for (int p = pb * 256; p < pb * 256 + 256; ++p)
    acc += syncv[p] * rdw1[(64 + p) * 512 + j];
  sc_part[pb * 512 + j] = acc;
}

// Readout MLP per batch row (final tick only). (1024 blocks x 512)
__global__ __launch_bounds__(512)
void k_read(const float* __restrict__ values_g, const float* __restrict__ sc_part,
            const float* __restrict__ rdw1,
            const float* __restrict__ rdg1, const float* __restrict__ rdbe1,
            const float* __restrict__ rdw2, const float* __restrict__ rdb2,
            const float* __restrict__ rdg2, const float* __restrict__ rdbe2,
            const float* __restrict__ rdw3, const float* __restrict__ rdb3,
            float* __restrict__ out) {
  int tid = threadIdx.x;
  int b = blockIdx.x;
  __shared__ float vals[64];
  __shared__ float r1[512];
  __shared__ float r2[64];
  __shared__ float red[16];
  if (tid < 64) vals[tid] = values_g[b * 64 + tid];
  __syncthreads();
  float u = sc_part[tid] + sc_part[512 + tid] + sc_part[1024 + tid] + sc_part[1536 + tid];
  for (int k = 0; k < 64; ++k) u += vals[k] * rdw1[k * 512 + tid];
  float s = wave_red_sum(u), s2 = wave_red_sum(u * u);
  int wid = tid >> 6, lane = tid & 63;
  if (lane == 0) { red[wid * 2] = s; red[wid * 2 + 1] = s2; }
  __syncthreads();
  float S = 0.f, S2 = 0.f;
#pragma unroll
  for (int w = 0; w < 8; ++w) { S += red[w * 2]; S2 += red[w * 2 + 1]; }
  float m = S * (1.f / 512.f), v = S2 * (1.f / 512.f) - m * m;
  float y = (u - m) * rsqrtf(v + 1e-5f) * rdg1[tid] + rdbe1[tid];
  r1[tid] = fmaxf(y, 0.f);
  __syncthreads();
  if (tid < 64) {
    float u2 = rdb2[tid];
    for (int k = 0; k < 512; ++k) u2 += r1[k] * rdw2[k * 64 + tid];
    float ss = wave_red_sum(u2), ss2 = wave_red_sum(u2 * u2);
    float mm = ss * (1.f / 64.f), vv = ss2 * (1.f / 64.f) - mm * mm;
    float y2 = (u2 - mm) * rsqrtf(vv + 1e-5f) * rdg2[tid] + rdbe2[tid];
    r2[tid] = fmaxf(y2, 0.f);
  }
  __syncthreads();
  if (tid < 10) {
    float o = rdb3[tid];
    for (int k = 0; k < 64; ++k) o += r2[k] * rdw3[k * 10 + tid];
    out[b * 10 + tid] = o;
  }
}

extern "C" void kernel_launch(void* const* d_in, const int* in_sizes, int n_in,
                              void* d_out, int out_size, void* d_ws, size_t ws_size,
                              hipStream_t stream) {
  const float* x     = (const float*)d_in[0];
  const float* post0 = (const float*)d_in[1];
  const float* pre0  = (const float*)d_in[2];
  const int*   pairs = (const int*)d_in[3];
  const float* decay = (const float*)d_in[4];
  const float* ie_w1 = (const float*)d_in[5];
  const float* ie_b1 = (const float*)d_in[6];
  const float* ie_g1 = (const float*)d_in[7];
  const float* ie_be1= (const float*)d_in[8];
  const float* ie_w2 = (const float*)d_in[9];
  const float* ie_b2 = (const float*)d_in[10];
  const float* ie_g2 = (const float*)d_in[11];
  const float* ie_be2= (const float*)d_in[12];
  const float* ie_w3 = (const float*)d_in[13];
  const float* ie_b3 = (const float*)d_in[14];
  const float* sy_w1 = (const float*)d_in[15];
  const float* sy_b1 = (const float*)d_in[16];
  const float* sy_g  = (const float*)d_in[17];
  const float* sy_be = (const float*)d_in[18];
  const float* sy_w2 = (const float*)d_in[19];
  const float* sy_b2 = (const float*)d_in[20];
  const float* nm_w1 = (const float*)d_in[21];
  const float* nm_b1 = (const float*)d_in[22];
  const float* nm_g  = (const float*)d_in[23];
  const float* nm_be = (const float*)d_in[24];
  const float* nm_w2 = (const float*)d_in[25];
  const float* nm_b2 = (const float*)d_in[26];
  // 27..32: key_w,key_b,val_w? no: 27 key_w, 28 key_b, 29 val_w, 30 val_b, 31 q_w, 32 q_b
  const float* val_w = (const float*)d_in[29];
  const float* val_b = (const float*)d_in[30];
  const float* rd_w1 = (const float*)d_in[33];
  const float* rd_b1 = (const float*)d_in[34];
  const float* rd_g1 = (const float*)d_in[35];
  const float* rd_be1= (const float*)d_in[36];
  const float* rd_w2 = (const float*)d_in[37];
  const float* rd_b2 = (const float*)d_in[38];
  const float* rd_g2 = (const float*)d_in[39];
  const float* rd_be2= (const float*)d_in[40];
  const float* rd_w3 = (const float*)d_in[41];
  const float* rd_b3 = (const float*)d_in[42];
  float* out = (float*)d_out;

  float* ws = (float*)d_ws;
  float* post    = ws;                 // 40960
  float* pre     = ws + 40960;         // 40960
  float* enc     = ws + 81920;         // 4096
  float* values  = ws + 86016;         // 65536
  float* c_part  = ws + 151552;        // 4096
  float* h       = ws + 155648;        // 262144
  float* hb_part = ws + 417792;        // 2048
  float* syncv   = ws + 419840;        // 1024
  float* sc_part = ws + 420864;        // 2048   -> total 422912 floats = 1.69 MB

  k_init<<<(N_ * M_ + 255) / 256, 256, 0, stream>>>(post0, pre0, post, pre);
  k_enc<<<B_ / 4, 128, 0, stream>>>(x, ie_w1, ie_b1, ie_g1, ie_be1,
                                    ie_w2, ie_b2, ie_g2, ie_be2,
                                    ie_w3, ie_b3, val_w, val_b, enc, values);
  for (int t = 0; t < T_; ++t) {
    k_synA<<<16, 256, 0, stream>>>(post, sy_w1, c_part);
    k_synB<<<B_, 256, 0, stream>>>(c_part, enc, sy_w1, sy_b1, sy_g, sy_be, h);
    k_colred<<<8, 256, 0, stream>>>(h, hb_part);
    k_pre<<<16, 256, 0, stream>>>(hb_part, sy_w2, sy_b2, pre);
    k_nm<<<N_ / 2, 256, 0, stream>>>(pre, nm_w1, nm_b1, nm_g, nm_be, nm_w2, nm_b2, post);
  }
  k_sync<<<4, 256, 0, stream>>>(post, pairs, decay, syncv);
  k_scpart<<<8, 256, 0, stream>>>(syncv, rd_w1, rd_b1, sc_part);
  k_read<<<B_, 512, 0, stream>>>(values, sc_part, rd_w1, rd_g1, rd_be1,
                                 rd_w2, rd_b2, rd_g2, rd_be2, rd_w3, rd_b3, out);
}

// Round 2
// 288.514 us; speedup vs baseline: 1.9620x; 1.9620x over previous
//
#include <hip/hip_runtime.h>

#define N_ 4096
#define M_ 10
#define T_ 10
#define B_ 1024
#define P_ 1024
#define AD_ 64

__device__ __forceinline__ float wave_red_sum(float v) {
#pragma unroll
  for (int m = 32; m >= 1; m >>= 1) v += __shfl_xor(v, m);
  return v;
}

// Copy initial state post0/pre0 -> workspace; also extract post_last column.
__global__ void k_init(const float* __restrict__ post0, const float* __restrict__ pre0,
                       float* __restrict__ post, float* __restrict__ pre,
                       float* __restrict__ post_last) {
  int i = blockIdx.x * blockDim.x + threadIdx.x;
  if (i < N_ * M_) { post[i] = post0[i]; pre[i] = pre0[i]; }
  if (i < N_) post_last[i] = post0[i * M_ + (M_ - 1)];
}

// Fused encoder: fx -> E1(LN,relu) -> E2(LN,relu) -> enc -> values. 8 batch rows/block.
#define EROWS 8
__global__ __launch_bounds__(128)
void k_enc(const float* __restrict__ x,
           const float* __restrict__ w1, const float* __restrict__ b1,
           const float* __restrict__ g1, const float* __restrict__ be1,
           const float* __restrict__ w2, const float* __restrict__ b2,
           const float* __restrict__ g2, const float* __restrict__ be2,
           const float* __restrict__ w3, const float* __restrict__ b3,
           const float* __restrict__ vw, const float* __restrict__ vb,
           float* __restrict__ enc_g, float* __restrict__ values_g) {
  const int tid = threadIdx.x;
  const int b0 = blockIdx.x * EROWS;
  __shared__ float fx[EROWS][784];
  __shared__ float e1[EROWS][128];
  __shared__ float e2[EROWS][32];
  __shared__ float encs[EROWS][4];
  __shared__ float red[2][EROWS][2];

  for (int i = tid; i < EROWS * 784; i += 128) {
    int r = i / 784, k = i - r * 784;
    fx[r][k] = x[(b0 + r) * 784 + k];
  }
  __syncthreads();

  float acc[EROWS];
#pragma unroll
  for (int r = 0; r < EROWS; ++r) acc[r] = 0.f;
  for (int k = 0; k < 784; ++k) {
    float w = w1[k * 128 + tid];
#pragma unroll
    for (int r = 0; r < EROWS; ++r) acc[r] += fx[r][k] * w;
  }
  float bb1 = b1[tid];
#pragma unroll
  for (int r = 0; r < EROWS; ++r) acc[r] += bb1;

  int wid = tid >> 6, lane = tid & 63;
#pragma unroll
  for (int r = 0; r < EROWS; ++r) {
    float s = wave_red_sum(acc[r]);
    float s2 = wave_red_sum(acc[r] * acc[r]);
    if (lane == 0) { red[wid][r][0] = s; red[wid][r][1] = s2; }
  }
  __syncthreads();
  float gg = g1[tid], bbe = be1[tid];
#pragma unroll
  for (int r = 0; r < EROWS; ++r) {
    float S = red[0][r][0] + red[1][r][0];
    float S2 = red[0][r][1] + red[1][r][1];
    float m = S * (1.f / 128.f);
    float v = S2 * (1.f / 128.f) - m * m;
    float y = (acc[r] - m) * rsqrtf(v + 1e-5f) * gg + bbe;
    e1[r][tid] = fmaxf(y, 0.f);
  }
  __syncthreads();

  // E2: 8 rows x 32 outs, 2 passes; LN over 32 via width-32 shuffles
#pragma unroll
  for (int rr = 0; rr < 2; ++rr) {
    int r = rr * 4 + (tid >> 5), j = tid & 31;
    float u = b2[j];
    for (int k = 0; k < 128; ++k) u += e1[r][k] * w2[k * 32 + j];
    float ss = u, ss2 = u * u;
#pragma unroll
    for (int m = 16; m >= 1; m >>= 1) { ss += __shfl_xor(ss, m, 32); ss2 += __shfl_xor(ss2, m, 32); }
    float mm = ss * (1.f / 32.f), vv = ss2 * (1.f / 32.f) - mm * mm;
    float y = (u - mm) * rsqrtf(vv + 1e-5f) * g2[j] + be2[j];
    e2[r][j] = fmaxf(y, 0.f);
  }
  __syncthreads();

  if (tid < EROWS * 4) {  // enc
    int r = tid >> 2, o = tid & 3;
    float u = b3[o];
    for (int k = 0; k < 32; ++k) u += e2[r][k] * w3[k * 4 + o];
    encs[r][o] = u;
    enc_g[(b0 + r) * 4 + o] = u;
  }
  __syncthreads();

  // values (softmax over size-1 axis == 1 -> att == values): 8 rows x 64
#pragma unroll
  for (int rr = 0; rr < 4; ++rr) {
    int r = rr * 2 + (tid >> 6), v = tid & 63;
    float u = vb[v];
#pragma unroll
    for (int o = 0; o < 4; ++o) u += encs[r][o] * vw[o * 64 + v];
    values_g[(b0 + r) * 64 + v] = u;
  }
}

// c_part[blk][j] = sum_{n in 64-chunk} post_last[n] * sy_w1[4+n][j]   (64 blocks x 256)
__global__ __launch_bounds__(256)
void k_synA(const float* __restrict__ post_last, const float* __restrict__ syw1,
            float* __restrict__ c_part) {
  int j = threadIdx.x;
  int n0 = blockIdx.x * 64;
  __shared__ float pl[64];
  if (j < 64) pl[j] = post_last[n0 + j];
  __syncthreads();
  float acc = 0.f;
  for (int i = 0; i < 64; ++i)
    acc += pl[i] * syw1[(4 + n0 + i) * 256 + j];
  c_part[blockIdx.x * 256 + j] = acc;
}

// Fused synB + batch-mean: 128 blocks x 8 rows. hb_part[blk][j] = sum over rows of relu(ln(u)).
__global__ __launch_bounds__(256)
void k_synB(const float* __restrict__ c_part, const float* __restrict__ enc_g,
            const float* __restrict__ syw1, const float* __restrict__ syb1,
            const float* __restrict__ syg, const float* __restrict__ sybe,
            float* __restrict__ hb_part) {
  int j = threadIdx.x;
  int b0 = blockIdx.x * 8;
  float cj = syb1[j];
#pragma unroll
  for (int r = 0; r < 64; ++r) cj += c_part[r * 256 + j];
  float gg = syg[j], bb = sybe[j];
  float w4[4];
#pragma unroll
  for (int o = 0; o < 4; ++o) w4[o] = syw1[o * 256 + j];
  __shared__ float encl[8][4];
  if (j < 32) encl[j >> 2][j & 3] = enc_g[(b0 + (j >> 2)) * 4 + (j & 3)];
  __shared__ float red[8];
  __syncthreads();
  int wid = j >> 6, lane = j & 63;
  float hacc = 0.f;
#pragma unroll
  for (int rr = 0; rr < 8; ++rr) {
    float u = cj;
#pragma unroll
    for (int o = 0; o < 4; ++o) u += encl[rr][o] * w4[o];
    float s = wave_red_sum(u), s2 = wave_red_sum(u * u);
    if (lane == 0) { red[wid * 2] = s; red[wid * 2 + 1] = s2; }
    __syncthreads();
    float S = red[0] + red[2] + red[4] + red[6];
    float S2 = red[1] + red[3] + red[5] + red[7];
    float m = S * (1.f / 256.f), v = S2 * (1.f / 256.f) - m * m;
    float y = (u - m) * rsqrtf(v + 1e-5f) * gg + bb;
    hacc += fmaxf(y, 0.f);
    __syncthreads();
  }
  hb_part[blockIdx.x * 256 + j] = hacc;
}

// npre[n] = hbar @ sy_w2 + sy_b2 ; shift pre row, append.  (64 blocks x 256, 4-way k-split)
__global__ __launch_bounds__(256)
void k_pre(const float* __restrict__ hb_part, const float* __restrict__ syw2,
           const float* __restrict__ syb2, float* __restrict__ pre) {
  __shared__ float hbar[256];
  __shared__ float part[4][64];
  int tid = threadIdx.x;
  float a = 0.f;
#pragma unroll
  for (int r = 0; r < 128; ++r) a += hb_part[r * 256 + tid];
  hbar[tid] = a * (1.f / 1024.f);
  __syncthreads();
  int kq = tid >> 6, nl = tid & 63;
  int n = blockIdx.x * 64 + nl;
  float u = 0.f;
#pragma unroll
  for (int kk = 0; kk < 64; ++kk) {
    int k = kq * 64 + kk;
    u += hbar[k] * syw2[k * N_ + n];
  }
  part[kq][nl] = u;
  __syncthreads();
  if (tid < 64) {
    int n2 = blockIdx.x * 64 + tid;
    float v = part[0][tid] + part[1][tid] + part[2][tid] + part[3][tid] + syb2[n2];
    float row[M_];
#pragma unroll
    for (int m = 1; m < M_; ++m) row[m - 1] = pre[n2 * M_ + m];
    row[M_ - 1] = v;
#pragma unroll
    for (int m = 0; m < M_; ++m) pre[n2 * M_ + m] = row[m];
  }
}

// Neuromodulator: per n: LN128(pre[n] @ nm_w1[n] + b1) relu, dot nm_w2[n]; shift post.
// 2048 blocks x 256 (2 rows per block). Also writes post_last.
__global__ __launch_bounds__(256)
void k_nm(const float* __restrict__ pre, const float* __restrict__ w1,
          const float* __restrict__ b1, const float* __restrict__ g,
          const float* __restrict__ be, const float* __restrict__ w2,
          const float* __restrict__ b2, float* __restrict__ post,
          float* __restrict__ post_last) {
  int tid = threadIdx.x;
  int grp = tid >> 7;
  int j = tid & 127;
  int n = blockIdx.x * 2 + grp;
  float prow[M_];
#pragma unroll
  for (int m = 0; m < M_; ++m) prow[m] = pre[n * M_ + m];
  float u = b1[n * 128 + j];
#pragma unroll
  for (int m = 0; m < M_; ++m) u += prow[m] * w1[(n * M_ + m) * 128 + j];
  __shared__ float red[8];
  float s = wave_red_sum(u), s2 = wave_red_sum(u * u);
  int wid = tid >> 6, lane = tid & 63;
  if (lane == 0) { red[wid * 2] = s; red[wid * 2 + 1] = s2; }
  __syncthreads();
  float S = red[grp * 4 + 0] + red[grp * 4 + 2];
  float S2 = red[grp * 4 + 1] + red[grp * 4 + 3];
  float m = S * (1.f / 128.f), v = S2 * (1.f / 128.f) - m * m;
  float y = (u - m) * rsqrtf(v + 1e-5f) * g[n * 128 + j] + be[n * 128 + j];
  y = fmaxf(y, 0.f);
  float d = y * w2[n * 128 + j];
  d = wave_red_sum(d);
  __syncthreads();
  if (lane == 0) red[wid] = d;
  __syncthreads();
  if (j == 0) {
    float npost = red[grp * 2] + red[grp * 2 + 1] + b2[n];
    float row[M_];
#pragma unroll
    for (int m2 = 1; m2 < M_; ++m2) row[m2 - 1] = post[n * M_ + m2];
    row[M_ - 1] = npost;
#pragma unroll
    for (int m2 = 0; m2 < M_; ++m2) post[n * M_ + m2] = row[m2];
    post_last[n] = npost;
  }
}

// sync[p] over final post (tick 9 => L = M = 10, full rows).  (4 blocks x 256)
__global__ __launch_bounds__(256)
void k_sync(const float* __restrict__ post, const int* __restrict__ pairs,
            const float* __restrict__ decay, float* __restrict__ syncv) {
  int p = blockIdx.x * 256 + threadIdx.x;
  if (p >= P_) return;
  int i = pairs[p * 2], jn = pairs[p * 2 + 1];
  float dc = decay[p];
  float num = 0.f, den = 0.f;
#pragma unroll
  for (int l = 0; l < M_; ++l) {
    float r = expf(-dc * (float)(M_ - 1 - l));
    num += post[i * M_ + l] * r * post[jn * M_ + l];
    den += r;
  }
  syncv[p] = num / (den + 1e-8f);
}

// sc_part[pb][j] partial of (sync @ rd_w1[64:])   (128 blocks: 64 p-chunks x 2 j-halves)
__global__ __launch_bounds__(256)
void k_scpart(const float* __restrict__ syncv, const float* __restrict__ rdw1,
              float* __restrict__ sc_part) {
  int j = (blockIdx.x & 1) * 256 + threadIdx.x;
  int pb = blockIdx.x >> 1;
  __shared__ float sv[16];
  if (threadIdx.x < 16) sv[threadIdx.x] = syncv[pb * 16 + threadIdx.x];
  __syncthreads();
  float acc = 0.f;
#pragma unroll
  for (int i = 0; i < 16; ++i)
    acc += sv[i] * rdw1[(64 + pb * 16 + i) * 512 + j];
  sc_part[pb * 512 + j] = acc;
}

// Reduce 64 partials -> sc[512] (+bias). (1 block x 512)
__global__ __launch_bounds__(512)
void k_scred(const float* __restrict__ sc_part, const float* __restrict__ rdb1,
             float* __restrict__ sc) {
  int tid = threadIdx.x;
  float a = rdb1[tid];
#pragma unroll
  for (int r = 0; r < 64; ++r) a += sc_part[r * 512 + tid];
  sc[tid] = a;
}

// Readout MLP, 4 batch rows/block (256 blocks x 512).
__global__ __launch_bounds__(512)
void k_read(const float* __restrict__ values_g, const float* __restrict__ sc,
            const float* __restrict__ rdw1,
            const float* __restrict__ rdg1, const float* __restrict__ rdbe1,
            const float* __restrict__ rdw2, const float* __restrict__ rdb2,
            const float* __restrict__ rdg2, const float* __restrict__ rdbe2,
            const float* __restrict__ rdw3, const float* __restrict__ rdb3,
            float* __restrict__ out) {
  int tid = threadIdx.x;
  int b0 = blockIdx.x * 4;
  __shared__ float vals[4][64];
  __shared__ float r1[4][512];
  __shared__ float r2[4][64];
  __shared__ float red[4][16];
  __shared__ float p2[8][4][64];
  for (int i = tid; i < 256; i += 512) {
    int r = i >> 6;
    vals[r][i & 63] = values_g[(b0 + r) * 64 + (i & 63)];
  }
  __syncthreads();
  float base = sc[tid];
  float u[4];
#pragma unroll
  for (int r = 0; r < 4; ++r) u[r] = base;
  for (int k = 0; k < 64; ++k) {
    float w = rdw1[k * 512 + tid];
#pragma unroll
    for (int r = 0; r < 4; ++r) u[r] += vals[r][k] * w;
  }
  int wid = tid >> 6, lane = tid & 63;
#pragma unroll
  for (int r = 0; r < 4; ++r) {
    float s = wave_red_sum(u[r]), s2 = wave_red_sum(u[r] * u[r]);
    if (lane == 0) { red[r][wid * 2] = s; red[r][wid * 2 + 1] = s2; }
  }
  __syncthreads();
  float gg = rdg1[tid], bb = rdbe1[tid];
#pragma unroll
  for (int r = 0; r < 4; ++r) {
    float S = 0.f, S2 = 0.f;
#pragma unroll
    for (int w = 0; w < 8; ++w) { S += red[r][w * 2]; S2 += red[r][w * 2 + 1]; }
    float m = S * (1.f / 512.f), v = S2 * (1.f / 512.f) - m * m;
    float y = (u[r] - m) * rsqrtf(v + 1e-5f) * gg + bb;
    r1[r][tid] = fmaxf(y, 0.f);
  }
  __syncthreads();
  // layer 2: 8 k-groups x 64 outs
  int o = tid & 63, kq = tid >> 6;
  float u2[4] = {0.f, 0.f, 0.f, 0.f};
#pragma unroll
  for (int kk = 0; kk < 64; ++kk) {
    int k = kq * 64 + kk;
    float w = rdw2[k * 64 + o];
#pragma unroll
    for (int r = 0; r < 4; ++r) u2[r] += r1[r][k] * w;
  }
#pragma unroll
  for (int r = 0; r < 4; ++r) p2[kq][r][o] = u2[r];
  __syncthreads();
  if (tid < 256) {
    int r = tid >> 6, o2 = tid & 63;
    float v = rdb2[o2];
#pragma unroll
    for (int gq = 0; gq < 8; ++gq) v += p2[gq][r][o2];
    float s = wave_red_sum(v), s2 = wave_red_sum(v * v);
    float m = s * (1.f / 64.f), var = s2 * (1.f / 64.f) - m * m;
    float y = (v - m) * rsqrtf(var + 1e-5f) * rdg2[o2] + rdbe2[o2];
    r2[r][o2] = fmaxf(y, 0.f);
  }
  __syncthreads();
  if (tid < 40) {
    int r = tid / 10, o3 = tid - r * 10;
    float acc = rdb3[o3];
#pragma unroll
    for (int k = 0; k < 64; ++k) acc += r2[r][k] * rdw3[k * 10 + o3];
    out[(b0 + r) * 10 + o3] = acc;
  }
}

extern "C" void kernel_launch(void* const* d_in, const int* in_sizes, int n_in,
                              void* d_out, int out_size, void* d_ws, size_t ws_size,
                              hipStream_t stream) {
  const float* x     = (const float*)d_in[0];
  const float* post0 = (const float*)d_in[1];
  const float* pre0  = (const float*)d_in[2];
  const int*   pairs = (const int*)d_in[3];
  const float* decay = (const float*)d_in[4];
  const float* ie_w1 = (const float*)d_in[5];
  const float* ie_b1 = (const float*)d_in[6];
  const float* ie_g1 = (const float*)d_in[7];
  const float* ie_be1= (const float*)d_in[8];
  const float* ie_w2 = (const float*)d_in[9];
  const float* ie_b2 = (const float*)d_in[10];
  const float* ie_g2 = (const float*)d_in[11];
  const float* ie_be2= (const float*)d_in[12];
  const float* ie_w3 = (const float*)d_in[13];
  const float* ie_b3 = (const float*)d_in[14];
  const float* sy_w1 = (const float*)d_in[15];
  const float* sy_b1 = (const float*)d_in[16];
  const float* sy_g  = (const float*)d_in[17];
  const float* sy_be = (const float*)d_in[18];
  const float* sy_w2 = (const float*)d_in[19];
  const float* sy_b2 = (const float*)d_in[20];
  const float* nm_w1 = (const float*)d_in[21];
  const float* nm_b1 = (const float*)d_in[22];
  const float* nm_g  = (const float*)d_in[23];
  const float* nm_be = (const float*)d_in[24];
  const float* nm_w2 = (const float*)d_in[25];
  const float* nm_b2 = (const float*)d_in[26];
  const float* val_w = (const float*)d_in[29];
  const float* val_b = (const float*)d_in[30];
  const float* rd_w1 = (const float*)d_in[33];
  const float* rd_b1 = (const float*)d_in[34];
  const float* rd_g1 = (const float*)d_in[35];
  const float* rd_be1= (const float*)d_in[36];
  const float* rd_w2 = (const float*)d_in[37];
  const float* rd_b2 = (const float*)d_in[38];
  const float* rd_g2 = (const float*)d_in[39];
  const float* rd_be2= (const float*)d_in[40];
  const float* rd_w3 = (const float*)d_in[41];
  const float* rd_b3 = (const float*)d_in[42];
  float* out = (float*)d_out;

  float* ws = (float*)d_ws;
  float* post      = ws;                  // 40960
  float* pre       = ws + 40960;          // 40960
  float* post_last = ws + 81920;          // 4096
  float* enc       = ws + 86016;          // 4096
  float* values    = ws + 90112;          // 65536
  float* c_part    = ws + 155648;         // 64*256 = 16384
  float* hb_part   = ws + 172032;         // 128*256 = 32768
  float* syncv     = ws + 204800;         // 1024
  float* sc_part   = ws + 205824;         // 64*512 = 32768
  float* sc        = ws + 238592;         // 512    -> total ~0.96 MB

  k_init<<<(N_ * M_ + 255) / 256, 256, 0, stream>>>(post0, pre0, post, pre, post_last);
  k_enc<<<B_ / EROWS, 128, 0, stream>>>(x, ie_w1, ie_b1, ie_g1, ie_be1,
                                        ie_w2, ie_b2, ie_g2, ie_be2,
                                        ie_w3, ie_b3, val_w, val_b, enc, values);
  for (int t = 0; t < T_; ++t) {
    k_synA<<<64, 256, 0, stream>>>(post_last, sy_w1, c_part);
    k_synB<<<128, 256, 0, stream>>>(c_part, enc, sy_w1, sy_b1, sy_g, sy_be, hb_part);
    k_pre<<<64, 256, 0, stream>>>(hb_part, sy_w2, sy_b2, pre);
    k_nm<<<N_ / 2, 256, 0, stream>>>(pre, nm_w1, nm_b1, nm_g, nm_be, nm_w2, nm_b2,
                                     post, post_last);
  }
  k_sync<<<4, 256, 0, stream>>>(post, pairs, decay, syncv);
  k_scpart<<<128, 256, 0, stream>>>(syncv, rd_w1, sc_part);
  k_scred<<<1, 512, 0, stream>>>(sc_part, rd_b1, sc);
  k_read<<<B_ / 4, 512, 0, stream>>>(values, sc, rd_w1, rd_g1, rd_be1,
                                     rd_w2, rd_b2, rd_g2, rd_be2, rd_w3, rd_b3, out);
}